// Round 6
// baseline (3591.009 us; speedup 1.0000x reference)
//
#include <hip/hip_runtime.h>
#include <hip/hip_bf16.h>
#include <hip/hip_cooperative_groups.h>
#include <math.h>

namespace cg = cooperative_groups;

#define B_    64
#define T_    24
#define IND_  25
#define HID_  64
#define NPIX  625

// padded-grid geometry
#define WP0   27
#define WP1   29
#define XSTR  32          // x-buf pixel stride (ushorts)
#define HSTR  72          // h-buf pixel stride (ushorts)
#define XROWS0 744
#define XROWS1 856
#define HROWS0 744
#define HROWS1 856
#define XB0   (XROWS0*XSTR)
#define XB1   (XROWS1*XSTR)
#define HB0   (HROWS0*HSTR)
#define HB1   (HROWS1*HSTR)
#define XB0T  (B_*XB0)        // 1,523,712
#define XB1T  (B_*XB1)        // 1,753,088
#define HB0T  (B_*HB0)        // 3,428,352
#define HB1T  (B_*HB1)        // 3,944,448
#define HPART (HB0T+HB1T)     // 7,372,800 per parity

// staged pixels / 16B chunks per branch
#define RST0  200
#define RST1  272
#define CH0   (RST0*9)    // 1800
#define CH1   (RST1*9)    // 2448

// final-conv combined input: [b][832 rows][128] bf16
#define HCROWS 832
#define HCB    (HCROWS*128)
#define HCTOT  (B_*HCB)

#define WFRAG_PER_BR (9*3*4*4*512)    // 221,184
#define WFRAG_TOT    (2*WFRAG_PER_BR)

typedef __bf16 bf16x8 __attribute__((ext_vector_type(8)));
typedef float  f32x4  __attribute__((ext_vector_type(4)));
typedef unsigned short ushort_t;
typedef unsigned int   uint_t;

typedef const __attribute__((address_space(1))) void as1_cvoid;
typedef __attribute__((address_space(3))) void as3_void;

__device__ __forceinline__ float sigmoidf_(float x) { return 1.f / (1.f + __expf(-x)); }
__device__ __forceinline__ float tanh_fast(float x) { return 2.f / (1.f + __expf(-2.f * x)) - 1.f; }
__device__ __forceinline__ ushort_t f2bf(float f) {
    unsigned int u = __float_as_uint(f);
    u += 0x7FFFu + ((u >> 16) & 1u);
    return (ushort_t)(u >> 16);
}
__device__ __forceinline__ float bf2f(ushort_t h) {
    return __uint_as_float(((unsigned int)h) << 16);
}

__global__ __launch_bounds__(256) void fill_zero_kernel(uint_t* __restrict__ p, int n) {
    int i = blockIdx.x * 256 + threadIdx.x;
    if (i < n) p[i] = 0u;
}

// Wfrag[br][tap][kk][wm][mf][lane][e]: m = wm*64 + gate*16 + ocl, gate=mf, oc=wm*16+l16.
__global__ __launch_bounds__(256) void repack_w_kernel(
    const float* __restrict__ w1, const float* __restrict__ w2, ushort_t* __restrict__ Wfrag)
{
    int id = blockIdx.x * 256 + threadIdx.x;
    if (id >= WFRAG_TOT) return;
    int e    = id & 7;
    int lane = (id >> 3) & 63;
    int mf   = (id >> 9) & 3;
    int wm   = (id >> 11) & 3;
    int rest = id >> 13;
    int kk   = rest % 3;
    int tap  = (rest / 3) % 9;
    int br   = rest / 27;
    int l16 = lane & 15, kh = lane >> 4;
    int gate = mf;
    int oc   = wm * 16 + l16;
    int k    = kh * 8 + e;
    int c;
    if (kk == 0)      c = (k < IND_) ? k : -1;
    else if (kk == 1) c = IND_ + k;
    else              c = IND_ + 32 + k;
    const float* w = br ? w2 : w1;
    float v = (c >= 0) ? w[((size_t)(gate * 64 + oc) * 89 + c) * 9 + tap] : 0.f;
    Wfrag[id] = f2bf(v);
}

__global__ __launch_bounds__(256) void repack_wc_kernel(
    const float* __restrict__ wc, ushort_t* __restrict__ Wc)
{
    int id = blockIdx.x * 256 + threadIdx.x;
    if (id >= 9 * 64 * 128) return;
    int k   = id % 128;
    int oc  = (id / 128) % 64;
    int tap = id / (128 * 64);
    Wc[id] = f2bf(wc[((size_t)(oc * 128) + k) * 9 + tap]);
}

// ---------------- persistent cooperative ConvLSTM kernel ----------------

__device__ __forceinline__ void ln_phase(
    const float* __restrict__ x, const float* __restrict__ gamma, const float* __restrict__ beta,
    ushort_t* __restrict__ xb, int tt, int bid, int tid)
{
    if (tid >= 157) return;
    const int p = bid * 157 + tid;
    if (p >= B_ * NPIX) return;
    const int b = p / NPIX, hw = p - b * NPIX;
    const int y = hw / 25, xx = hw - y * 25;
    const float* xp = x + ((size_t)(b * T_ + tt) * IND_) * NPIX + hw;
    float v[IND_];
    float s = 0.f;
#pragma unroll
    for (int c = 0; c < IND_; ++c) { v[c] = xp[c * NPIX]; s += v[c]; }
    const float mu = s * (1.f / IND_);
    float ss = 0.f;
#pragma unroll
    for (int c = 0; c < IND_; ++c) { float dd = v[c] - mu; ss += dd * dd; }
    const float rstd = rsqrtf(ss * (1.f / IND_) + 1e-5f);
    ushort_t us[IND_];
#pragma unroll
    for (int c = 0; c < IND_; ++c) us[c] = f2bf((v[c] - mu) * rstd * gamma[c] + beta[c]);
    uint4 q0, q1, q2;
    q0.x = us[0] | ((uint_t)us[1] << 16);  q0.y = us[2] | ((uint_t)us[3] << 16);
    q0.z = us[4] | ((uint_t)us[5] << 16);  q0.w = us[6] | ((uint_t)us[7] << 16);
    q1.x = us[8] | ((uint_t)us[9] << 16);  q1.y = us[10] | ((uint_t)us[11] << 16);
    q1.z = us[12] | ((uint_t)us[13] << 16); q1.w = us[14] | ((uint_t)us[15] << 16);
    q2.x = us[16] | ((uint_t)us[17] << 16); q2.y = us[18] | ((uint_t)us[19] << 16);
    q2.z = us[20] | ((uint_t)us[21] << 16); q2.w = us[22] | ((uint_t)us[23] << 16);
    const int par = tt & 1;
    ushort_t* o0 = xb + (size_t)par * XB0T + (size_t)b * XB0 + (size_t)((y + 1) * WP0 + (xx + 1)) * XSTR;
    ushort_t* o1 = xb + 2 * (size_t)XB0T + (size_t)par * XB1T + (size_t)b * XB1 + (size_t)((y + 2) * WP1 + (xx + 2)) * XSTR;
    *(uint4*)o0 = q0; *(uint4*)(o0 + 8) = q1; *(uint4*)(o0 + 16) = q2; o0[24] = us[24];
    *(uint4*)o1 = q0; *(uint4*)(o1 + 8) = q1; *(uint4*)(o1 + 16) = q2; o1[24] = us[24];
}

__device__ __forceinline__ void stage_tile(
    int tile, int cur, int tid, const ushort_t* __restrict__ hb, ushort_t* ldsbuf)
{
    const int rg = tile % 5, b = (tile / 5) & 63, br = tile / 320;
    const int Wp = 25 + 2 * (1 + br);
    const ushort_t* hc = hb + (size_t)cur * HPART +
                         (br ? (size_t)HB0T + (size_t)b * HB1 : (size_t)b * HB0);
    const int u0 = rg * 5 * Wp;
    const int CH = br ? CH1 : CH0;
    const char* gsrc = (const char*)(hc + (size_t)u0 * HSTR);
    const int wave_u = tid & 448;
#pragma unroll
    for (int j = 0; j < 5; ++j) {
        const int i = j * 512 + tid;
        if (i < CH) {
            __builtin_amdgcn_global_load_lds(
                (as1_cvoid*)(gsrc + (size_t)i * 16),
                (as3_void*)((char*)ldsbuf + (size_t)(j * 512 + wave_u) * 16),
                16, 0, 0);
        }
    }
}

__device__ __forceinline__ void conv_tile(
    int tile, int cur, int nxt, int tid,
    const ushort_t* __restrict__ xb, ushort_t* __restrict__ hb,
    const ushort_t* __restrict__ Wfrag,
    const float* __restrict__ bias1, const float* __restrict__ bias2,
    const ushort_t* __restrict__ lds, f32x4 (&cacc)[5])
{
    const int rg = tile % 5, b = (tile / 5) & 63, br = tile / 320;
    const int d = 1 + br;
    const int Wp = 25 + 2 * d;
    const ushort_t* __restrict__ xbuf =
        xb + (br ? 2 * (size_t)XB0T + (size_t)cur * XB1T + (size_t)b * XB1
                 : (size_t)cur * XB0T + (size_t)b * XB0);
    ushort_t* __restrict__ hnx =
        hb + (size_t)nxt * HPART + (br ? (size_t)HB0T + (size_t)b * HB1 : (size_t)b * HB0);
    const float* __restrict__ bias = br ? bias2 : bias1;
    const ushort_t* __restrict__ WFb = Wfrag + (size_t)br * WFRAG_PER_BR;

    const int w    = tid >> 6, lane = tid & 63;
    const int wm   = w & 3, wn = w >> 2;
    const int l16  = lane & 15, kh = lane >> 4;
    const int koff = kh * 8;
    const int u0   = rg * 5 * Wp;

    f32x4 acc[4][5];
#pragma unroll
    for (int i = 0; i < 4; ++i)
#pragma unroll
        for (int j = 0; j < 5; ++j) acc[i][j] = (f32x4){0.f, 0.f, 0.f, 0.f};

    int baserel[5];
#pragma unroll
    for (int nf = 0; nf < 5; ++nf) {
        int n = wn * 80 + nf * 16 + l16;
        baserel[nf] = (n >> 5) * Wp + (n & 31);
    }

    for (int tap = 0; tap < 9; ++tap) {
        const int ky = tap / 3, kx = tap - 3 * ky;
        const int toff = (ky * Wp + kx) * d;
        const ushort_t* __restrict__ WT = WFb + (size_t)(tap * 3) * 8192 + wm * 2048 + lane * 8;
        // kk=0: x from global x-buf
        {
            bf16x8 af[4], bfr[5];
#pragma unroll
            for (int mf = 0; mf < 4; ++mf)
                af[mf] = *(const bf16x8*)(WT + mf * 512);
#pragma unroll
            for (int nf = 0; nf < 5; ++nf)
                bfr[nf] = *(const bf16x8*)(xbuf + (size_t)(u0 + baserel[nf] + toff) * XSTR + koff);
#pragma unroll
            for (int mf = 0; mf < 4; ++mf)
#pragma unroll
                for (int nf = 0; nf < 5; ++nf)
                    acc[mf][nf] = __builtin_amdgcn_mfma_f32_16x16x32_bf16(
                        af[mf], bfr[nf], acc[mf][nf], 0, 0, 0);
        }
        // kk=1,2: h from LDS
#pragma unroll
        for (int kkh = 0; kkh < 2; ++kkh) {
            bf16x8 af[4], bfr[5];
#pragma unroll
            for (int mf = 0; mf < 4; ++mf)
                af[mf] = *(const bf16x8*)(WT + (size_t)(kkh + 1) * 8192 + mf * 512);
#pragma unroll
            for (int nf = 0; nf < 5; ++nf)
                bfr[nf] = *(const bf16x8*)(lds + (baserel[nf] + toff) * HSTR + kkh * 32 + koff);
#pragma unroll
            for (int mf = 0; mf < 4; ++mf)
#pragma unroll
                for (int nf = 0; nf < 5; ++nf)
                    acc[mf][nf] = __builtin_amdgcn_mfma_f32_16x16x32_bf16(
                        af[mf], bfr[nf], acc[mf][nf], 0, 0, 0);
        }
    }

    // Epilogue: gate = mf, oc = wm*16 + kh*4 + r; c stays in registers.
    const int oc0 = wm * 16 + kh * 4;
    float bi4[4], bf4[4], bo4[4], bg4[4];
#pragma unroll
    for (int r = 0; r < 4; ++r) {
        bi4[r] = bias[oc0 + r];
        bf4[r] = bias[64 + oc0 + r];
        bo4[r] = bias[128 + oc0 + r];
        bg4[r] = bias[192 + oc0 + r];
    }
#pragma unroll
    for (int nf = 0; nf < 5; ++nf) {
        const int n = wn * 80 + nf * 16 + l16;
        const int xx = n & 31;
        if (xx >= 25) continue;
        const int y = rg * 5 + (n >> 5);
        ushort_t hs[4];
#pragma unroll
        for (int r = 0; r < 4; ++r) {
            const float zi = acc[0][nf][r] + bi4[r];
            const float zf = acc[1][nf][r] + bf4[r];
            const float zo = acc[2][nf][r] + bo4[r];
            const float zg = acc[3][nf][r] + bg4[r];
            const float cn = sigmoidf_(zf) * cacc[nf][r] + sigmoidf_(zi) * tanh_fast(zg);
            cacc[nf][r] = cn;
            hs[r] = f2bf(sigmoidf_(zo) * tanh_fast(cn));
        }
        uint2 hv;
        hv.x = (uint_t)hs[0] | ((uint_t)hs[1] << 16);
        hv.y = (uint_t)hs[2] | ((uint_t)hs[3] << 16);
        *(uint2*)(hnx + (size_t)((y + d) * Wp + (xx + d)) * HSTR + oc0) = hv;
    }
}

// 256 blocks x 512 thr; block bid owns tiles {bid, bid+256, bid+512(<640)} for all 24 steps.
__global__ __launch_bounds__(512, 2) void persist_kernel(
    const float* __restrict__ x, const float* __restrict__ ln_g, const float* __restrict__ ln_b,
    ushort_t* __restrict__ xb, ushort_t* __restrict__ hb, const ushort_t* __restrict__ Wfrag,
    const float* __restrict__ b_l1, const float* __restrict__ b_l2)
{
    cg::grid_group grid = cg::this_grid();
    const int bid = blockIdx.x, tid = threadIdx.x;
    const bool has2 = (bid < 128);

    __shared__ ushort_t lds[2][RST1 * HSTR];   // 78,336 B

    f32x4 c0[5], c1[5], c2[5];
#pragma unroll
    for (int j = 0; j < 5; ++j) {
        c0[j] = (f32x4){0.f, 0.f, 0.f, 0.f};
        c1[j] = (f32x4){0.f, 0.f, 0.f, 0.f};
        c2[j] = (f32x4){0.f, 0.f, 0.f, 0.f};
    }

    ln_phase(x, ln_g, ln_b, xb, 0, bid, tid);
    grid.sync();

    for (int t = 0; t < T_; ++t) {
        const int cur = t & 1, nxt = cur ^ 1;
        stage_tile(bid, cur, tid, hb, lds[0]);
        if (t + 1 < T_) ln_phase(x, ln_g, ln_b, xb, t + 1, bid, tid);
        __syncthreads();                                   // lds[0] ready
        stage_tile(bid + 256, cur, tid, hb, lds[1]);
        conv_tile(bid, cur, nxt, tid, xb, hb, Wfrag, b_l1, b_l2, lds[0], c0);
        __syncthreads();                                   // lds[1] ready, lds[0] free
        if (has2) stage_tile(bid + 512, cur, tid, hb, lds[0]);
        conv_tile(bid + 256, cur, nxt, tid, xb, hb, Wfrag, b_l1, b_l2, lds[1], c1);
        if (has2) {
            __syncthreads();                               // lds[0] ready
            conv_tile(bid + 512, cur, nxt, tid, xb, hb, Wfrag, b_l1, b_l2, lds[0], c2);
        }
        grid.sync();
    }
}

// ---------------- tail (proven in R3-R5) ----------------

__global__ __launch_bounds__(256) void combine_h_kernel(
    const ushort_t* __restrict__ h0, const ushort_t* __restrict__ h1, ushort_t* __restrict__ Hc)
{
    int id = blockIdx.x * 256 + threadIdx.x;
    if (id >= B_ * NPIX * 128) return;
    int k   = id % 128;
    int pix = (id / 128) % NPIX;
    int b   = id / (128 * NPIX);
    int y = pix / 25, xx = pix % 25;
    ushort_t v;
    if (k < 64) v = h0[(size_t)b * HB0 + (size_t)((y + 1) * WP0 + (xx + 1)) * HSTR + k];
    else        v = h1[(size_t)b * HB1 + (size_t)((y + 2) * WP1 + (xx + 2)) * HSTR + (k - 64)];
    Hc[(size_t)b * HCB + (size_t)((y + 1) * 27 + (xx + 1)) * 128 + k] = v;
}

__global__ __launch_bounds__(512) void conv_mfma_kernel(
    const ushort_t* __restrict__ Hc, const ushort_t* __restrict__ Wc,
    const float* __restrict__ bc, float* __restrict__ conv_out)
{
    const int rg = blockIdx.x;
    const int b  = blockIdx.y;
    const ushort_t* __restrict__ Hb = Hc + (size_t)b * HCB;

    const int tid  = threadIdx.x;
    const int w    = tid >> 6, lane = tid & 63;
    const int wm   = w & 1, wn = w >> 1;
    const int l16  = lane & 15, kh = lane >> 4;
    const int koff = kh * 8;

    f32x4 acc[2][2];
#pragma unroll
    for (int i = 0; i < 2; ++i)
#pragma unroll
        for (int j = 0; j < 2; ++j) acc[i][j] = (f32x4){0.f, 0.f, 0.f, 0.f};

    int baserow[2];
#pragma unroll
    for (int nf = 0; nf < 2; ++nf) {
        int n = wn * 32 + nf * 16 + l16;
        baserow[nf] = (rg * 4 + (n >> 5)) * 27 + (n & 31);
    }
    const ushort_t* __restrict__ Wm = Wc + (size_t)(wm * 32 + l16) * 128 + koff;

    for (int tap = 0; tap < 9; ++tap) {
        const int ky = tap / 3, kx = tap - 3 * ky;
        const int toff = ky * 27 + kx;
        const ushort_t* __restrict__ Wt = Wm + (size_t)tap * (64 * 128);
        const ushort_t* Urow[2];
#pragma unroll
        for (int nf = 0; nf < 2; ++nf)
            Urow[nf] = Hb + (size_t)(baserow[nf] + toff) * 128 + koff;
#pragma unroll
        for (int kk = 0; kk < 4; ++kk) {
            bf16x8 af[2], bfr[2];
#pragma unroll
            for (int mf = 0; mf < 2; ++mf)
                af[mf] = *(const bf16x8*)(Wt + mf * 16 * 128 + kk * 32);
#pragma unroll
            for (int nf = 0; nf < 2; ++nf)
                bfr[nf] = *(const bf16x8*)(Urow[nf] + kk * 32);
#pragma unroll
            for (int mf = 0; mf < 2; ++mf)
#pragma unroll
                for (int nf = 0; nf < 2; ++nf)
                    acc[mf][nf] = __builtin_amdgcn_mfma_f32_16x16x32_bf16(
                        af[mf], bfr[nf], acc[mf][nf], 0, 0, 0);
        }
    }

#pragma unroll
    for (int mf = 0; mf < 2; ++mf) {
#pragma unroll
        for (int nf = 0; nf < 2; ++nf) {
            const int n = wn * 32 + nf * 16 + l16;
            const int xx = n & 31;
            if (xx >= 25) continue;
            const int y = rg * 4 + wn;
            if (y >= 25) continue;
#pragma unroll
            for (int r = 0; r < 4; ++r) {
                const int oc = wm * 32 + mf * 16 + kh * 4 + r;
                const float v = fmaxf(acc[mf][nf][r] + bc[oc], 0.f);
                conv_out[((size_t)(b * 64 + oc)) * NPIX + y * 25 + xx] = v;
            }
        }
    }
}

__global__ __launch_bounds__(256) void pool_kernel(
    const float* __restrict__ conv_out, float* __restrict__ pool)
{
    int id = blockIdx.x * 256 + threadIdx.x;
    if (id >= B_ * 64 * 144) return;
    int px = id % 12;
    int py = (id / 12) % 12;
    int oc = (id / 144) % 64;
    int b  = id / (144 * 64);
    const float* p = conv_out + ((size_t)(b * 64 + oc)) * NPIX;
    const int cy = 2 * py, cx = 2 * px;
    float mx = fmaxf(fmaxf(p[cy * 25 + cx], p[cy * 25 + cx + 1]),
                     fmaxf(p[(cy + 1) * 25 + cx], p[(cy + 1) * 25 + cx + 1]));
    pool[(size_t)b * 9216 + oc * 144 + py * 12 + px] = mx;
}

__global__ __launch_bounds__(256) void fc1_kernel(
    const float* __restrict__ pool, const float* __restrict__ w1, const float* __restrict__ b1,
    float* __restrict__ f1)
{
    const int task = blockIdx.x * 4 + (threadIdx.x >> 6);
    const int lane = threadIdx.x & 63;
    const int b = task >> 6, oc = task & 63;
    const float* pr = pool + (size_t)b * 9216;
    const float* wr = w1 + (size_t)oc * 9216;
    float acc = 0.f;
#pragma unroll 4
    for (int it = 0; it < 36; ++it) {
        const int k = it * 256 + lane * 4;
        const float4 p = *(const float4*)(pr + k);
        const float4 ww = *(const float4*)(wr + k);
        acc += p.x * ww.x + p.y * ww.y + p.z * ww.z + p.w * ww.w;
    }
#pragma unroll
    for (int off = 32; off > 0; off >>= 1) acc += __shfl_down(acc, off);
    if (lane == 0) f1[b * 64 + oc] = fmaxf(acc + b1[oc], 0.f);
}

__global__ __launch_bounds__(64) void head2_kernel(
    const float* __restrict__ f1,
    const float* __restrict__ w2, const float* __restrict__ b2,
    const float* __restrict__ w3, const float* __restrict__ b3,
    float* __restrict__ out)
{
    const int b = blockIdx.x;
    __shared__ float f1l[64];
    __shared__ float f2[32];
    const int tid = threadIdx.x;
    f1l[tid] = f1[b * 64 + tid];
    __syncthreads();
    if (tid < 32) {
        float acc = b2[tid];
        const float* wr = w2 + (size_t)tid * 64;
#pragma unroll
        for (int k = 0; k < 64; ++k) acc += f1l[k] * wr[k];
        f2[tid] = fmaxf(acc, 0.f);
    }
    __syncthreads();
    if (tid == 0) {
        float y0 = b3[0], y1 = b3[1];
#pragma unroll
        for (int k = 0; k < 32; ++k) { y0 += f2[k] * w3[k]; y1 += f2[k] * w3[32 + k]; }
        const float m = fmaxf(y0, y1);
        const float lse = m + logf(expf(y0 - m) + expf(y1 - m));
        out[b * 2 + 0] = y0 - lse;
        out[b * 2 + 1] = y1 - lse;
    }
}

extern "C" void kernel_launch(void* const* d_in, const int* in_sizes, int n_in,
                              void* d_out, int out_size, void* d_ws, size_t ws_size,
                              hipStream_t stream) {
    const float* x    = (const float*)d_in[0];
    const float* ln_g = (const float*)d_in[1];
    const float* ln_b = (const float*)d_in[2];
    const float* w_l1 = (const float*)d_in[3];
    const float* b_l1 = (const float*)d_in[4];
    const float* w_l2 = (const float*)d_in[5];
    const float* b_l2 = (const float*)d_in[6];
    const float* w_c  = (const float*)d_in[7];
    const float* b_c  = (const float*)d_in[8];
    const float* w_f1 = (const float*)d_in[9];
    const float* b_f1 = (const float*)d_in[10];
    const float* w_f2 = (const float*)d_in[11];
    const float* b_f2 = (const float*)d_in[12];
    const float* w_f3 = (const float*)d_in[13];
    const float* b_f3 = (const float*)d_in[14];

    // ws layout (ushort units):
    //   xb: [xb0 par0][xb0 par1][xb1 par0][xb1 par1] = 6,553,600
    //   hb: [parity0: h0,h1][parity1: h0,h1]         = 14,745,600
    //   Wfrag 442,368 | Wc 73,728 | f1 8,192
    //   aliases at tail: Hc -> hb parity1 region; conv_out+pool -> xb region.
    // Total ~43.6 MB.
    ushort_t* wsu = (ushort_t*)d_ws;
    uint_t*   wsi = (uint_t*)d_ws;

    ushort_t* xb    = wsu;
    ushort_t* hb    = wsu + 2 * (size_t)XB0T + 2 * (size_t)XB1T;
    ushort_t* Wfrag = hb + 2 * (size_t)HPART;
    ushort_t* Wc    = Wfrag + WFRAG_TOT;
    float*    f1    = (float*)(Wc + 73728);
    ushort_t* Hc    = hb + HPART;              // parity-1 halves (dead at tail)
    float*    conv_out = (float*)wsu;          // xb region (dead at tail)
    float*    pool  = (float*)wsu + 2560000;

    // zero xb (borders) + hb (h0 state + borders), both parities
    const int n_fill = (int)((2 * (size_t)XB0T + 2 * (size_t)XB1T + 2 * (size_t)HPART) / 2);
    fill_zero_kernel<<<(n_fill + 255) / 256, 256, 0, stream>>>(wsi, n_fill);
    repack_w_kernel<<<(WFRAG_TOT + 255) / 256, 256, 0, stream>>>(w_l1, w_l2, Wfrag);
    repack_wc_kernel<<<(9 * 64 * 128 + 255) / 256, 256, 0, stream>>>(w_c, Wc);

    void* kargs[8];
    kargs[0] = (void*)&x;    kargs[1] = (void*)&ln_g; kargs[2] = (void*)&ln_b;
    kargs[3] = (void*)&xb;   kargs[4] = (void*)&hb;   kargs[5] = (void*)&Wfrag;
    kargs[6] = (void*)&b_l1; kargs[7] = (void*)&b_l2;
    hipLaunchCooperativeKernel((void*)persist_kernel, dim3(256), dim3(512), kargs, 0, stream);

    // final h in parity 0: h0 at hb, h1 at hb + HB0T
    fill_zero_kernel<<<(HCTOT / 2 + 255) / 256, 256, 0, stream>>>((uint_t*)Hc, HCTOT / 2);
    combine_h_kernel<<<(B_ * NPIX * 128 + 255) / 256, 256, 0, stream>>>(hb, hb + HB0T, Hc);
    conv_mfma_kernel<<<dim3(7, B_), 512, 0, stream>>>(Hc, Wc, b_c, conv_out);
    pool_kernel<<<(B_ * 64 * 144 + 255) / 256, 256, 0, stream>>>(conv_out, pool);
    fc1_kernel<<<1024, 256, 0, stream>>>(pool, w_f1, b_f1, f1);
    head2_kernel<<<B_, 64, 0, stream>>>(f1, w_f2, b_f2, w_f3, b_f3, (float*)d_out);
}